// Round 7
// baseline (154.424 us; speedup 1.0000x reference)
//
#include <hip/hip_runtime.h>

#define PH 7
#define PW 7
#define NB 49
#define SSCALE 0.0625f
#define CC 256
#define HH 200
#define WW 200
#define HWSZ (HH * WW)
#define ROWB (WW * 4)             // bytes per feature row

#define CPW 2                     // channels per wave
#define CPG 8                     // channels per block (4 waves x CPW)
#define SROW 14                   // y-interpolated sample rows
#define NSLOT 11                  // float4 slots per row
#define PITCHF 44
#define CH_T  (SROW * PITCHF + 4) // 620 floats per channel region
#define RSTR  5                   // rowstreams/pass: lanes 0..54 stage
#define NR    2                   // rois per block (software-pipelined)

typedef float f4 __attribute__((ext_vector_type(4)));

// Scheduling fence only — NO raw loads, NO hand-counted vmcnt. The compiler
// derives all s_waitcnt itself (correct per-lane/per-register, unlike v13).
#define SFENCE __builtin_amdgcn_sched_barrier(0)
#define LGKM0 do { asm volatile("s_waitcnt lgkmcnt(0)" ::: "memory"); \
                   __builtin_amdgcn_sched_barrier(0); } while (0)

__global__ __launch_bounds__(256, 6) void roi_align_v14(
    const float* __restrict__ features, const float* __restrict__ rois,
    float* __restrict__ out, int N)
{
    __shared__ float lds[CPG * CH_T];   // 19,840 B

    // grid(8, N/NR, 4): blockIdx.x IS the xcd under linear round-robin.
    // cgroup = z*8 + x -> each XCD sweeps all roi-chunks of one cgroup
    // (2.56 MB slab < 4 MB XCD L2) before moving to the next.
    const int xcd   = blockIdx.x;
    const int rbase = blockIdx.y * NR;
    const int cg    = blockIdx.z * 8 + xcd;

    const int t    = threadIdx.x;
    const int wid  = __builtin_amdgcn_readfirstlane(t >> 6);  // SGPR bases
    const int lane = t & 63;

    const int c = cg * CPG + wid * CPW;          // wave's first channel
    float* tb0 = &lds[wid * CPW * CH_T];         // wave-private, 2 x CH_T

    const int  sl   = lane % NSLOT;              // once
    const int  r0   = lane / NSLOT;              // 0..5
    const bool lact = lane < RSTR * NSLOT;       // lanes 0..54 stage
    const int  vla0 = r0 * PITCHF + (sl << 2);   // lds float base; +220/pass
    const int  phl  = lane / PW;                 // once
    const int  pwl  = lane - phl * PW;

    float x1, y1, bw, bh; int col0a, vcolB, curN, curN_c;
    const float *fb0, *fb1;
    f4 va0[3], vb0[3], va1[3], vb1[3];
    float wA[3], wB[3];
    float swx0[2], swx1[2]; int soA[2];

#define DECODE(Q) {                                                          \
    int nb_ = rbase + (Q); if (nb_ > N - 1) nb_ = N - 1;                     \
    const float* r_ = rois + (size_t)nb_ * 5;                                \
    int   b_  = (int)r_[0];                                                  \
    x1 = r_[1] * SSCALE; y1 = r_[2] * SSCALE;                                \
    float x2_ = r_[3] * SSCALE, y2_ = r_[4] * SSCALE;                        \
    bw = fmaxf(x2_ - x1, 1.f) * (1.f / PW);                                  \
    bh = fmaxf(y2_ - y1, 1.f) * (1.f / PH);                                  \
    col0a = min((int)fmaxf(x1 + 0.25f * bw, 0.f), WW - 1) & ~3;              \
    vcolB = min(col0a + (sl << 2), WW - 4) << 2;                             \
    fb0 = features + (size_t)(b_ * CC + c) * HWSZ; fb1 = fb0 + HWSZ;         \
    curN = nb_; }

    // pass P: y-geometry + issue 4 PLAIN loads (2 taps x 2 channels)
#define SLOAD(P, PRED) { if (lact && (PRED)) {                               \
    int   s_  = r0 + (P) * RSTR;                                             \
    float yb_ = (float)(s_ >> 1) + ((s_ & 1) ? 0.75f : 0.25f);               \
    float y_  = y1 + yb_ * bh;                                               \
    bool  vy_ = (y_ >= -1.f) && (y_ <= (float)HH);                           \
    float cy_ = fmaxf(y_, 0.f);                                              \
    int   yl_ = min((int)cy_, HH - 1);                                       \
    float fy_ = cy_ - (float)yl_;      /* inc=0 at clamp: weights sum ok */  \
    int  inB_ = (yl_ < HH - 1) ? ROWB : 0;                                   \
    wA[P] = vy_ ? (1.f - fy_) : 0.f;                                         \
    wB[P] = vy_ ? fy_ : 0.f;                                                 \
    int off_  = yl_ * ROWB + vcolB;                                          \
    va0[P] = *(const f4*)((const char*)fb0 + off_);                          \
    vb0[P] = *(const f4*)((const char*)fb0 + off_ + inB_);                   \
    va1[P] = *(const f4*)((const char*)fb1 + off_);                          \
    vb1[P] = *(const f4*)((const char*)fb1 + off_ + inB_); } }

#define CWRITE(P, PRED) { if (lact && (PRED)) {                              \
    *(f4*)&tb0[vla0 + (P) * (RSTR * PITCHF)] =                               \
        wA[P] * va0[P] + wB[P] * vb0[P];                                     \
    *(f4*)&tb0[CH_T + vla0 + (P) * (RSTR * PITCHF)] =                        \
        wA[P] * va1[P] + wB[P] * vb1[P]; } }

#define XSETUP() { _Pragma("unroll") for (int i = 0; i < 2; ++i) {           \
    float sf_ = i ? 0.75f : 0.25f;                                           \
    float x_  = x1 + ((float)pwl + sf_) * bw;                                \
    bool  vx_ = (x_ >= -1.f) && (x_ <= (float)WW);                           \
    float cx_ = fmaxf(x_, 0.f);                                              \
    int   xl_ = min((int)cx_, WW - 1);                                       \
    float fx_ = (xl_ >= WW - 1) ? 0.f : (cx_ - (float)xl_);                  \
    swx0[i] = vx_ ? (1.f - fx_) : 0.f;                                       \
    swx1[i] = vx_ ? fx_ : 0.f;                                               \
    soA[i]  = xl_ - col0a; }                                                 \
    curN_c = curN; }

#define COMPUTE_STORE() { if (lane < NB) {                                   \
    float a0 = 0.f, a1 = 0.f;                                                \
    _Pragma("unroll") for (int iy = 0; iy < 2; ++iy) {                       \
        const float* p0 = tb0 + (2 * phl + iy) * PITCHF;                     \
        const float* p1 = p0 + CH_T;                                         \
        _Pragma("unroll") for (int i = 0; i < 2; ++i) {                      \
            a0 += swx0[i] * p0[soA[i]] + swx1[i] * p0[soA[i] + 1];           \
            a1 += swx0[i] * p1[soA[i]] + swx1[i] * p1[soA[i] + 1]; } }       \
    float* ob = out + (size_t)(curN_c * CC + c) * NB + lane;                 \
    ob[0]  = a0 * 0.25f;                                                     \
    ob[NB] = a1 * 0.25f; } }

    // ---- prologue: stage item 0 with 2 passes (8 loads) pinned in flight ----
    DECODE(0);
    SLOAD(0, true); SLOAD(1, true);
    SFENCE;                              // loads may not sink below this
    CWRITE(0, true);                     // compiler inserts counted vmcnt
    SLOAD(2, r0 < SROW - 2 * RSTR);      // rows 10..13 (r0 < 4)
    SFENCE;
    CWRITE(1, true);
    CWRITE(2, r0 < SROW - 2 * RSTR);

    // ---- pipelined item loop: loads(q+1) in flight across compute(q) ----
    #pragma unroll
    for (int q = 0; q < NR; ++q) {
        XSETUP();                        // roi q x-weights (before DECODE q+1)
        if (q < NR - 1) {
            DECODE(q + 1);
            SLOAD(0, true); SLOAD(1, true);   // 8 loads live over compute
            SFENCE;
        }
        LGKM0;                           // item q's ds_writes visible (in-order)
        COMPUTE_STORE();
        if (q < NR - 1) {
            SFENCE;                      // keep next-item writes below reads
            CWRITE(0, true);             // p0 arrived during compute: ~no stall
            SLOAD(2, r0 < SROW - 2 * RSTR);
            SFENCE;
            CWRITE(1, true);
            CWRITE(2, r0 < SROW - 2 * RSTR);
        }
    }
}

extern "C" void kernel_launch(void* const* d_in, const int* in_sizes, int n_in,
                              void* d_out, int out_size, void* d_ws, size_t ws_size,
                              hipStream_t stream) {
    const float* features = (const float*)d_in[0];
    const float* rois     = (const float*)d_in[1];
    float*       out      = (float*)d_out;

    int N = in_sizes[1] / 5;                 // 512 rois
    int chunks = (N + NR - 1) / NR;          // 256

    dim3 grid(8, chunks, CC / CPG / 8);      // (xcd, roi-chunk, cgroup-phase)
    roi_align_v14<<<grid, 256, 0, stream>>>(features, rois, out, N);
}